// Round 16
// baseline (88.371 us; speedup 1.0000x reference)
//
#include <hip/hip_runtime.h>
#include <hip/hip_bf16.h>

typedef __attribute__((ext_vector_type(8))) short bf16x8;
typedef __attribute__((ext_vector_type(4))) float f32x4;

#define NN 4096
#define DD 64
#define LL 16
// sqrt(log2(e)): prescaling x by this makes dot = log2(e)*<x,x'>, so
// K = exp(dot - hi - hj) becomes exp2(dots - hsi - hsj) -> bare v_exp_f32.
#define SCALE 1.2011224087864498f
// skip threshold (base-2 exponent): skipped terms <= 2^-24 each.
#define THR -24.0f

__device__ __forceinline__ ushort f2bf(float f) {
    unsigned int u = __float_as_uint(f);
    unsigned int r = u + 0x7FFFu + ((u >> 16) & 1u);
    return (ushort)(r >> 16);
}
__device__ __forceinline__ float bf2f(ushort u) {
    return __uint_as_float(((unsigned int)u) << 16);
}

__device__ __forceinline__ void gload_lds16(const void* g, void* l) {
    __builtin_amdgcn_global_load_lds((const __attribute__((address_space(1))) unsigned int*)g,
                                     (__attribute__((address_space(3))) unsigned int*)l, 16, 0, 0);
}
__device__ __forceinline__ void gload_lds4(const void* g, void* l) {
    __builtin_amdgcn_global_load_lds((const __attribute__((address_space(1))) unsigned int*)g,
                                     (__attribute__((address_space(3))) unsigned int*)l, 4, 0, 0);
}

// Transpose (N,D,L) fp32 -> (L,N,D) bf16 with per-row 16B-chunk XOR swizzle
// (chunk co of row n stored at co ^ (n&7)), values prescaled by SCALE, and
// h[l][n] = 0.5 * sum_d xs_bf16^2 (fp32, from the SAME bf16 values MFMA sees).
// Also zero-inits the accumulator region (a_raw|b_raw|t1 contiguous) and out.
__global__ void prep_kernel(const float* __restrict__ X, const float* __restrict__ Y,
                            ushort* __restrict__ Xb, ushort* __restrict__ Yb,
                            float* __restrict__ hx, float* __restrict__ hy,
                            float* __restrict__ zacc, float* __restrict__ out) {
    const float* in = blockIdx.y ? Y : X;
    ushort* outb    = blockIdx.y ? Yb : Xb;
    float* h        = blockIdx.y ? hy : hx;

    __shared__ float lds[64 * 17];
    __shared__ float psum[16][17];

    int n = blockIdx.x;
    int t = threadIdx.x;
    const float* row = in + (size_t)n * (DD * LL);

    // fold the memsets: zacc = a_raw|b_raw|t1 = 131088 floats, contiguous
    if (blockIdx.y == 0) {
        if (t < 32) zacc[n * 32 + t] = 0.f;                    // 4096*32 = 131072
        if (n == 0) {
            if (t >= 32 && t < 48) zacc[131072 + (t - 32)] = 0.f;  // t1[16]
            if (t == 48) out[0] = 0.f;
        }
    }

    // vectorized load: 256 threads x float4 = 1024 floats (e = d*16 + l)
    {
        float4 v = *reinterpret_cast<const float4*>(row + 4 * t);
        int d = t >> 2, l0 = (t & 3) * 4;
        lds[d * 17 + l0 + 0] = v.x;
        lds[d * 17 + l0 + 1] = v.y;
        lds[d * 17 + l0 + 2] = v.z;
        lds[d * 17 + l0 + 3] = v.w;
    }
    __syncthreads();

    int l = t >> 4, c = t & 15;
    float p = 0.f;
    ushort4 w;
    {
        float v0 = lds[(c * 4 + 0) * 17 + l] * SCALE;
        float v1 = lds[(c * 4 + 1) * 17 + l] * SCALE;
        float v2 = lds[(c * 4 + 2) * 17 + l] * SCALE;
        float v3 = lds[(c * 4 + 3) * 17 + l] * SCALE;
        ushort u0 = f2bf(v0), u1 = f2bf(v1), u2 = f2bf(v2), u3 = f2bf(v3);
        float b0 = bf2f(u0), b1 = bf2f(u1), b2 = bf2f(u2), b3 = bf2f(u3);
        p = b0 * b0 + b1 * b1 + b2 * b2 + b3 * b3;
        w.x = u0; w.y = u1; w.z = u2; w.w = u3;
    }
    int cs = (c >> 1) ^ (n & 7);
    *reinterpret_cast<ushort4*>(outb + ((size_t)l * NN + n) * DD + cs * 8 + (c & 1) * 4) = w;

    psum[l][c] = p;
    __syncthreads();
    if (t < 16) {
        float s = 0.f;
#pragma unroll
        for (int i = 0; i < 16; ++i) s += psum[t][i];
        h[t * NN + n] = 0.5f * s;
    }
}

// LDS: 8 buffers x 8448 B; TWO tiles consumed per barrier, pair m+2 staged
// at the top of pair-iteration m (buffers (2m+4)&7,(2m+5)&7 never collide with
// pair m reads or the slowest wave's pair m-1 reads).
// Per buffer: [X 32x128B swizzled][Y 32x128B][h 256B = hx32,hy32].
#define BUF_BYTES 8448
#define H_OFF 8192
#define NBUF 8

// Uniform 3 VMEM ops per wave per stage (2x gload16 + 1x gload4 h-dup).
__device__ __forceinline__ void stage_tile(char* smem, int buf, int wave, int lane,
                                           const ushort* __restrict__ Xl, const ushort* __restrict__ Yl,
                                           const float* __restrict__ hxl, const float* __restrict__ hyl,
                                           int jb) {
    char* base = smem + buf * BUF_BYTES;
    const ushort* mat = (wave < 2) ? Xl : Yl;
#pragma unroll
    for (int q = 0; q < 2; ++q) {
        int ridx = wave * 2 + q;                  // 0..7 -> mat*4 + rowgroup
        int rbase = (ridx & 3) * 8;
        const ushort* src = mat + (size_t)(jb + rbase + (lane >> 3)) * DD + (lane & 7) * 8;
        gload_lds16(src, base + ridx * 1024);
    }
    // all waves duplicate-stage h (identical data, benign race, uniform vmcnt count)
    const float* hsrc = (lane < 32) ? (hxl + jb + lane) : (hyl + jb + (lane - 32));
    gload_lds4(hsrc, base + H_OFF);
}

// Triangular fused kernel, 256-row i-tiles. Grid = 16 l x 8 pairs x 4 segs = 512
// (R5 mapping). Pair p owns i-tiles {p, 15-p}; per i-tile ti, j-units jt in
// [8ti, 128); pair total 136 = 4 segments x 34 contiguous (cnt always EVEN).
// Band units (jt-8ti < 8): diagonal 256x256 block computed fully, weight 1,
// row sums only. Strict-upper: weight 2 for T1, col sums mirrored.
// Per wave: 64i x 32j per tile, 2 tiles per barrier; BOTH tiles' fragments get
// their own registers and are ds_read back-to-back after the barrier (kills the
// WAR serialization that made tile2's ds_reads wait on tile1's MFMA drain).
__global__ __launch_bounds__(256, 2) void hsic_tri(
    const ushort* __restrict__ Xb, const ushort* __restrict__ Yb,
    const float* __restrict__ hx, const float* __restrict__ hy,
    float* __restrict__ a_raw, float* __restrict__ b_raw, float* __restrict__ t1) {

    int blk = blockIdx.x;                       // 512
    int l = (blk & 7) * 2 + ((blk >> 3) & 1);   // XCD-pinned l pair
    int rest = blk >> 4;                        // 0..31
    int p = rest >> 2;                          // 0..7
    int seg = rest & 3;                         // 0..3
    int c = 128 - 8 * p;                        // units in phase A (ti = p)
    int u0 = seg * 34, u1 = u0 + 34;

    int wave = threadIdx.x >> 6;
    int lane = threadIdx.x & 63;
    int lrow = lane & 15;
    int khi  = lane >> 4;

    const ushort* Xl = Xb + (size_t)l * (NN * DD);
    const ushort* Yl = Yb + (size_t)l * (NN * DD);
    const float* hxl = hx + l * NN;
    const float* hyl = hy + l * NN;

    __shared__ __align__(16) char smem[NBUF * BUF_BYTES];

    float t1_1 = 0.f, t1_2 = 0.f;

    // per-lane LDS byte offsets for B fragments (constant)
    int offb[2][2];
#pragma unroll
    for (int cg = 0; cg < 2; ++cg)
#pragma unroll
        for (int kc = 0; kc < 2; ++kc)
            offb[cg][kc] = (cg * 16 + lrow) * 128 + (((kc * 4 + khi) ^ (lrow & 7)) * 16);

    auto run_phase = [&](int ti, int jt0, int cnt) {
        __syncthreads();                  // protect buffers from previous phase
        int ibase = ti * 256 + wave * 64;

        bf16x8 ax[4][2], ay[4][2];
        f32x4 nhxi4[4], nhyi4[4];
#pragma unroll
        for (int rg = 0; rg < 4; ++rg) {
            int arow = ibase + rg * 16 + lrow;
#pragma unroll
            for (int kc = 0; kc < 2; ++kc) {
                int cs = (kc * 4 + khi) ^ (arow & 7);
                ax[rg][kc] = *reinterpret_cast<const bf16x8*>(Xl + (size_t)arow * DD + cs * 8);
                ay[rg][kc] = *reinterpret_cast<const bf16x8*>(Yl + (size_t)arow * DD + cs * 8);
            }
            int crow = ibase + rg * 16 + khi * 4;
            f32x4 hv = *reinterpret_cast<const f32x4*>(hxl + crow);
            nhxi4[rg] = -hv;
            f32x4 hw = *reinterpret_cast<const f32x4*>(hyl + crow);
            nhyi4[rg] = -hw;
        }

        float rpx[4][4] = {}, rpy[4][4] = {};

        // fragment load from an LDS buffer into caller-owned (iteration-local) regs
        auto load_tile = [&](const char* bufc, bf16x8 (&bfx)[2][2], bf16x8 (&bfy)[2][2],
                             float (&hxj)[2], float (&hyj)[2]) {
            const float* hbuf = (const float*)(bufc + H_OFF);
#pragma unroll
            for (int cg = 0; cg < 2; ++cg) {
                hxj[cg] = hbuf[cg * 16 + lrow];
                hyj[cg] = hbuf[32 + cg * 16 + lrow];
#pragma unroll
                for (int kc = 0; kc < 2; ++kc) {
                    bfx[cg][kc] = *reinterpret_cast<const bf16x8*>(bufc + offb[cg][kc]);
                    bfy[cg][kc] = *reinterpret_cast<const bf16x8*>(bufc + 4096 + offb[cg][kc]);
                }
            }
        };

        // compute on pre-loaded fragments: MFMA, skip-test, epilogue
        auto compute_from = [&](const bf16x8 (&bfx)[2][2], const bf16x8 (&bfy)[2][2],
                                const float (&hxj)[2], const float (&hyj)[2], int k) {
            int jt = jt0 + k;
            int jb = jt * 32;
            bool band = (jt - 8 * ti) < 8;

            // C init = -(h_i + h_j); MFMA output is the full base-2 exponent
            f32x4 gx[4][2], gy[4][2];
#pragma unroll
            for (int rg = 0; rg < 4; ++rg)
#pragma unroll
                for (int cg = 0; cg < 2; ++cg) {
                    gx[rg][cg] = nhxi4[rg] - hxj[cg];
                    gy[rg][cg] = nhyi4[rg] - hyj[cg];
                }

#pragma unroll
            for (int rg = 0; rg < 4; ++rg)
#pragma unroll
                for (int cg = 0; cg < 2; ++cg)
#pragma unroll
                    for (int kc = 0; kc < 2; ++kc) {
                        gx[rg][cg] = __builtin_amdgcn_mfma_f32_16x16x32_bf16(ax[rg][kc], bfx[cg][kc], gx[rg][cg], 0, 0, 0);
                        gy[rg][cg] = __builtin_amdgcn_mfma_f32_16x16x32_bf16(ay[rg][kc], bfy[cg][kc], gy[rg][cg], 0, 0, 0);
                    }

            // max over all 64 exponents (left-nested triples -> v_max3), one branch
            float mt[16];
#pragma unroll
            for (int rg = 0; rg < 4; ++rg)
#pragma unroll
                for (int cg = 0; cg < 2; ++cg) {
                    int idx = rg * 2 + cg;
                    mt[idx]     = fmaxf(fmaxf(fmaxf(gx[rg][cg][0], gx[rg][cg][1]), gx[rg][cg][2]), gx[rg][cg][3]);
                    mt[8 + idx] = fmaxf(fmaxf(fmaxf(gy[rg][cg][0], gy[rg][cg][1]), gy[rg][cg][2]), gy[rg][cg][3]);
                }
            float m0 = fmaxf(fmaxf(fmaxf(mt[0], mt[1]), mt[2]), mt[3]);
            float m1 = fmaxf(fmaxf(fmaxf(mt[4], mt[5]), mt[6]), mt[7]);
            float m2 = fmaxf(fmaxf(fmaxf(mt[8], mt[9]), mt[10]), mt[11]);
            float m3 = fmaxf(fmaxf(fmaxf(mt[12], mt[13]), mt[14]), mt[15]);
            float mall = fmaxf(fmaxf(m0, m1), fmaxf(m2, m3));

            if (__ballot(mall >= THR)) {
                float cax[2] = {0.f, 0.f}, cay[2] = {0.f, 0.f};
#pragma unroll
                for (int rg = 0; rg < 4; ++rg)
#pragma unroll
                    for (int cg = 0; cg < 2; ++cg)
#pragma unroll
                        for (int q = 0; q < 4; ++q) {
                            float kxv = __builtin_exp2f(gx[rg][cg][q]);
                            float kyv = __builtin_exp2f(gy[rg][cg][q]);
                            rpx[rg][q] += kxv;
                            rpy[rg][q] += kyv;
                            float prod = kxv * kyv;
                            if (band) {
                                t1_1 += prod;
                            } else {
                                t1_2 += prod;
                                cax[cg] += kxv;
                                cay[cg] += kyv;
                            }
                        }
                if (!band) {
#pragma unroll
                    for (int cg = 0; cg < 2; ++cg) {
                        float vx = cax[cg], vy = cay[cg];
                        vx += __shfl_xor(vx, 16); vx += __shfl_xor(vx, 32);
                        vy += __shfl_xor(vy, 16); vy += __shfl_xor(vy, 32);
                        if (khi == 0) {
                            atomicAdd(&a_raw[l * NN + jb + cg * 16 + lrow], vx);
                            atomicAdd(&b_raw[l * NN + jb + cg * 16 + lrow], vy);
                        }
                    }
                }
            }
        };

        // prologue: stage pairs 0 and 1 (tiles 0..3, capped)
        int npro = cnt < 4 ? cnt : 4;
        for (int s = 0; s < npro; ++s)
            stage_tile(smem, s, wave, lane, Xl, Yl, hxl, hyl, (jt0 + s) * 32);

        // main loop: one barrier per PAIR of tiles; cnt is always even
        for (int base = 0; base < cnt; base += 2) {
            if (base + 4 < cnt)
                stage_tile(smem, (base + 4) & (NBUF - 1), wave, lane, Xl, Yl, hxl, hyl, (jt0 + base + 4) * 32);
            if (base + 5 < cnt)
                stage_tile(smem, (base + 5) & (NBUF - 1), wave, lane, Xl, Yl, hxl, hyl, (jt0 + base + 5) * 32);

            // counted wait: pair `base` retired; 12/9/6/3 newest ops may remain
            int rem = cnt - base - 2;             // tiles staged beyond this pair
            if (rem >= 4)      asm volatile("s_waitcnt vmcnt(12)" ::: "memory");
            else if (rem == 3) asm volatile("s_waitcnt vmcnt(9)"  ::: "memory");
            else if (rem == 2) asm volatile("s_waitcnt vmcnt(6)"  ::: "memory");
            else if (rem == 1) asm volatile("s_waitcnt vmcnt(3)"  ::: "memory");
            else               asm volatile("s_waitcnt vmcnt(0)"  ::: "memory");
            __builtin_amdgcn_s_barrier();
            __builtin_amdgcn_sched_barrier(0);

            const char* b0 = smem + (base & (NBUF - 1)) * BUF_BYTES;
            bool has1 = (base + 1 < cnt);
            const char* b1 = has1 ? smem + ((base + 1) & (NBUF - 1)) * BUF_BYTES : b0;

            // both tiles' fragments in SEPARATE registers, loaded back-to-back:
            // tile1's ds_reads no longer WAR-wait on tile0's MFMA consumption.
            bf16x8 f0x[2][2], f0y[2][2], f1x[2][2], f1y[2][2];
            float h0x[2], h0y[2], h1x[2], h1y[2];
            load_tile(b0, f0x, f0y, h0x, h0y);
            load_tile(b1, f1x, f1y, h1x, h1y);

            compute_from(f0x, f0y, h0x, h0y, base);
            if (has1) compute_from(f1x, f1y, h1x, h1y, base + 1);
        }

        // flush row sums for this i-tile
#pragma unroll
        for (int rg = 0; rg < 4; ++rg)
#pragma unroll
            for (int q = 0; q < 4; ++q) {
                float vx = rpx[rg][q], vy = rpy[rg][q];
#pragma unroll
                for (int sh = 1; sh < 16; sh <<= 1) {
                    vx += __shfl_xor(vx, sh);
                    vy += __shfl_xor(vy, sh);
                }
                if (lrow == 0) {
                    int row = ibase + rg * 16 + khi * 4 + q;
                    atomicAdd(&a_raw[l * NN + row], vx);
                    atomicAdd(&b_raw[l * NN + row], vy);
                }
            }
    };

    // phase A: ti = p, units [u0, min(u1,c)), jt = 8p + u
    int a_lo = u0, a_hi = (u1 < c) ? u1 : c;
    if (a_lo < a_hi) run_phase(p, 8 * p + a_lo, a_hi - a_lo);

    // phase B: ti = 15-p, units [max(u0,c), u1), jt = 8(15-p) + (u - c)
    int b_lo = (u0 > c) ? u0 : c, b_hi = u1;
    if (b_lo < b_hi) run_phase(15 - p, 8 * (15 - p) + (b_lo - c), b_hi - b_lo);

    float v = t1_1 + 2.f * t1_2;
#pragma unroll
    for (int sh = 1; sh < 64; sh <<= 1) v += __shfl_xor(v, sh);
    if (lane == 0) atomicAdd(&t1[l], v);
}

// One block per l; S_l = T1 - (2/n) sum A_i B_i + (sum A)(sum B)/n^2; atomicAdd into out.
__global__ void finalize_kernel(const float* __restrict__ a_raw, const float* __restrict__ b_raw,
                                const float* __restrict__ t1, float* __restrict__ out) {
    int l = blockIdx.x;
    int t = threadIdx.x;
    int lane = t & 63, w = t >> 6;

    float sab = 0.f, sa = 0.f, sb = 0.f;
    for (int i = t; i < NN; i += 256) {
        float av = a_raw[l * NN + i], bv = b_raw[l * NN + i];
        sab = __builtin_fmaf(av, bv, sab);
        sa += av;
        sb += bv;
    }
#pragma unroll
    for (int s = 1; s < 64; s <<= 1) {
        sab += __shfl_xor(sab, s);
        sa  += __shfl_xor(sa, s);
        sb  += __shfl_xor(sb, s);
    }
    __shared__ float sh[3][4];
    if (lane == 0) { sh[0][w] = sab; sh[1][w] = sa; sh[2][w] = sb; }
    __syncthreads();
    if (t == 0) {
        float rab = sh[0][0] + sh[0][1] + sh[0][2] + sh[0][3];
        float ra  = sh[1][0] + sh[1][1] + sh[1][2] + sh[1][3];
        float rb  = sh[2][0] + sh[2][1] + sh[2][2] + sh[2][3];
        const float n = (float)NN;
        float S = t1[l] - (2.f / n) * rab + (ra * rb) / (n * n);
        atomicAdd(out, S / (4095.f * 4095.f));
    }
}

extern "C" void kernel_launch(void* const* d_in, const int* in_sizes, int n_in,
                              void* d_out, int out_size, void* d_ws, size_t ws_size,
                              hipStream_t stream) {
    const float* X = (const float*)d_in[0];
    const float* Y = (const float*)d_in[1];
    float* out = (float*)d_out;
    char* ws = (char*)d_ws;

    const size_t XB_OFF  = 0;                       // L*N*D bf16 = 8388608 B
    const size_t YB_OFF  = 8388608;
    const size_t HX_OFF  = 16777216;                // L*N fp32
    const size_t HY_OFF  = 17039360;
    const size_t A_OFF   = 17301504;                // L*N fp32
    const size_t B_OFF   = 17563648;
    const size_t T1_OFF  = 17825792;                // L fp32

    ushort* Xb  = (ushort*)(ws + XB_OFF);
    ushort* Yb  = (ushort*)(ws + YB_OFF);
    float* hx   = (float*)(ws + HX_OFF);
    float* hy   = (float*)(ws + HY_OFF);
    float* a_raw = (float*)(ws + A_OFF);
    float* b_raw = (float*)(ws + B_OFF);
    float* t1    = (float*)(ws + T1_OFF);

    // zero-init of a_raw|b_raw|t1|out is folded into prep_kernel (y==0 blocks)
    prep_kernel<<<dim3(NN, 2), 256, 0, stream>>>(X, Y, Xb, Yb, hx, hy, a_raw, out);
    hsic_tri<<<512, 256, 0, stream>>>(Xb, Yb, hx, hy, a_raw, b_raw, t1);
    finalize_kernel<<<LL, 256, 0, stream>>>(a_raw, b_raw, t1, out);
}

// Round 17
// 79.574 us; speedup vs baseline: 1.1105x; 1.1105x over previous
//
#include <hip/hip_runtime.h>
#include <hip/hip_bf16.h>

typedef __attribute__((ext_vector_type(8))) short bf16x8;
typedef __attribute__((ext_vector_type(4))) float f32x4;

#define NN 4096
#define DD 64
#define LL 16
// sqrt(log2(e)): prescaling x by this makes dot = log2(e)*<x,x'>, so
// K = exp(dot - hi - hj) becomes exp2(dots - hsi - hsj) -> bare v_exp_f32.
#define SCALE 1.2011224087864498f
// skip threshold (base-2 exponent): skipped terms <= 2^-24 each.
#define THR -24.0f

__device__ __forceinline__ ushort f2bf(float f) {
    unsigned int u = __float_as_uint(f);
    unsigned int r = u + 0x7FFFu + ((u >> 16) & 1u);
    return (ushort)(r >> 16);
}
__device__ __forceinline__ float bf2f(ushort u) {
    return __uint_as_float(((unsigned int)u) << 16);
}

__device__ __forceinline__ void gload_lds16(const void* g, void* l) {
    __builtin_amdgcn_global_load_lds((const __attribute__((address_space(1))) unsigned int*)g,
                                     (__attribute__((address_space(3))) unsigned int*)l, 16, 0, 0);
}
__device__ __forceinline__ void gload_lds4(const void* g, void* l) {
    __builtin_amdgcn_global_load_lds((const __attribute__((address_space(1))) unsigned int*)g,
                                     (__attribute__((address_space(3))) unsigned int*)l, 4, 0, 0);
}

// Transpose (N,D,L) fp32 -> (L,N,D) bf16 with per-row 16B-chunk XOR swizzle
// (chunk co of row n stored at co ^ (n&7)), values prescaled by SCALE, and
// h[l][n] = 0.5 * sum_d xs_bf16^2 (fp32, from the SAME bf16 values MFMA sees).
// Also zero-inits the accumulator region (a_raw|b_raw|t1 contiguous) and out,
// replacing two hipMemsetAsync launches (prep completes before hsic_tri).
__global__ void prep_kernel(const float* __restrict__ X, const float* __restrict__ Y,
                            ushort* __restrict__ Xb, ushort* __restrict__ Yb,
                            float* __restrict__ hx, float* __restrict__ hy,
                            float* __restrict__ zacc, float* __restrict__ out) {
    const float* in = blockIdx.y ? Y : X;
    ushort* outb    = blockIdx.y ? Yb : Xb;
    float* h        = blockIdx.y ? hy : hx;

    __shared__ float lds[64 * 17];
    __shared__ float psum[16][17];

    int n = blockIdx.x;
    int t = threadIdx.x;
    const float* row = in + (size_t)n * (DD * LL);

    // fold the memsets: zacc = a_raw|b_raw|t1 = 131088 floats, contiguous
    if (blockIdx.y == 0) {
        if (t < 32) zacc[n * 32 + t] = 0.f;                    // 4096*32 = 131072
        if (n == 0) {
            if (t >= 32 && t < 48) zacc[131072 + (t - 32)] = 0.f;  // t1[16]
            if (t == 48) out[0] = 0.f;
        }
    }

    // vectorized load: 256 threads x float4 = 1024 floats (e = d*16 + l)
    {
        float4 v = *reinterpret_cast<const float4*>(row + 4 * t);
        int d = t >> 2, l0 = (t & 3) * 4;
        lds[d * 17 + l0 + 0] = v.x;
        lds[d * 17 + l0 + 1] = v.y;
        lds[d * 17 + l0 + 2] = v.z;
        lds[d * 17 + l0 + 3] = v.w;
    }
    __syncthreads();

    int l = t >> 4, c = t & 15;
    float p = 0.f;
    ushort4 w;
    {
        float v0 = lds[(c * 4 + 0) * 17 + l] * SCALE;
        float v1 = lds[(c * 4 + 1) * 17 + l] * SCALE;
        float v2 = lds[(c * 4 + 2) * 17 + l] * SCALE;
        float v3 = lds[(c * 4 + 3) * 17 + l] * SCALE;
        ushort u0 = f2bf(v0), u1 = f2bf(v1), u2 = f2bf(v2), u3 = f2bf(v3);
        float b0 = bf2f(u0), b1 = bf2f(u1), b2 = bf2f(u2), b3 = bf2f(u3);
        p = b0 * b0 + b1 * b1 + b2 * b2 + b3 * b3;
        w.x = u0; w.y = u1; w.z = u2; w.w = u3;
    }
    int cs = (c >> 1) ^ (n & 7);
    *reinterpret_cast<ushort4*>(outb + ((size_t)l * NN + n) * DD + cs * 8 + (c & 1) * 4) = w;

    psum[l][c] = p;
    __syncthreads();
    if (t < 16) {
        float s = 0.f;
#pragma unroll
        for (int i = 0; i < 16; ++i) s += psum[t][i];
        h[t * NN + n] = 0.5f * s;
    }
}

// LDS: 8 buffers x 8448 B; TWO tiles consumed per barrier, pair m+2 staged
// at the top of pair-iteration m (buffers (2m+4)&7,(2m+5)&7 never collide with
// pair m reads or the slowest wave's pair m-1 reads).
// Per buffer: [X 32x128B swizzled][Y 32x128B][h 256B = hx32,hy32].
#define BUF_BYTES 8448
#define H_OFF 8192
#define NBUF 8

// Uniform 3 VMEM ops per wave per stage (2x gload16 + 1x gload4 h-dup).
__device__ __forceinline__ void stage_tile(char* smem, int buf, int wave, int lane,
                                           const ushort* __restrict__ Xl, const ushort* __restrict__ Yl,
                                           const float* __restrict__ hxl, const float* __restrict__ hyl,
                                           int jb) {
    char* base = smem + buf * BUF_BYTES;
    const ushort* mat = (wave < 2) ? Xl : Yl;
#pragma unroll
    for (int q = 0; q < 2; ++q) {
        int ridx = wave * 2 + q;                  // 0..7 -> mat*4 + rowgroup
        int rbase = (ridx & 3) * 8;
        const ushort* src = mat + (size_t)(jb + rbase + (lane >> 3)) * DD + (lane & 7) * 8;
        gload_lds16(src, base + ridx * 1024);
    }
    // all waves duplicate-stage h (identical data, benign race, uniform vmcnt count)
    const float* hsrc = (lane < 32) ? (hxl + jb + lane) : (hyl + jb + (lane - 32));
    gload_lds4(hsrc, base + H_OFF);
}

// Triangular fused kernel, 256-row i-tiles. Grid = 16 l x 8 pairs x 4 segs = 512
// (R5 mapping). Pair p owns i-tiles {p, 15-p}; per i-tile ti, j-units jt in
// [8ti, 128); pair total 136 = 4 segments x 34 contiguous. Band units
// (jt-8ti < 8): diagonal 256x256 block computed fully, weight 1, row sums only.
// Strict-upper: weight 2 for T1, col sums mirrored. Per wave: 64i x 32j per
// tile, 2 tiles per barrier. [Best measured config: tri 65.0 us, round 10/15.]
__global__ __launch_bounds__(256, 2) void hsic_tri(
    const ushort* __restrict__ Xb, const ushort* __restrict__ Yb,
    const float* __restrict__ hx, const float* __restrict__ hy,
    float* __restrict__ a_raw, float* __restrict__ b_raw, float* __restrict__ t1) {

    int blk = blockIdx.x;                       // 512
    int l = (blk & 7) * 2 + ((blk >> 3) & 1);   // XCD-pinned l pair
    int rest = blk >> 4;                        // 0..31
    int p = rest >> 2;                          // 0..7
    int seg = rest & 3;                         // 0..3
    int c = 128 - 8 * p;                        // units in phase A (ti = p)
    int u0 = seg * 34, u1 = u0 + 34;

    int wave = threadIdx.x >> 6;
    int lane = threadIdx.x & 63;
    int lrow = lane & 15;
    int khi  = lane >> 4;

    const ushort* Xl = Xb + (size_t)l * (NN * DD);
    const ushort* Yl = Yb + (size_t)l * (NN * DD);
    const float* hxl = hx + l * NN;
    const float* hyl = hy + l * NN;

    __shared__ __align__(16) char smem[NBUF * BUF_BYTES];

    float t1_1 = 0.f, t1_2 = 0.f;

    // per-lane LDS byte offsets for B fragments (constant)
    int offb[2][2];
#pragma unroll
    for (int cg = 0; cg < 2; ++cg)
#pragma unroll
        for (int kc = 0; kc < 2; ++kc)
            offb[cg][kc] = (cg * 16 + lrow) * 128 + (((kc * 4 + khi) ^ (lrow & 7)) * 16);

    auto run_phase = [&](int ti, int jt0, int cnt) {
        __syncthreads();                  // protect buffers from previous phase
        int ibase = ti * 256 + wave * 64;

        bf16x8 ax[4][2], ay[4][2];
        f32x4 nhxi4[4], nhyi4[4];
#pragma unroll
        for (int rg = 0; rg < 4; ++rg) {
            int arow = ibase + rg * 16 + lrow;
#pragma unroll
            for (int kc = 0; kc < 2; ++kc) {
                int cs = (kc * 4 + khi) ^ (arow & 7);
                ax[rg][kc] = *reinterpret_cast<const bf16x8*>(Xl + (size_t)arow * DD + cs * 8);
                ay[rg][kc] = *reinterpret_cast<const bf16x8*>(Yl + (size_t)arow * DD + cs * 8);
            }
            int crow = ibase + rg * 16 + khi * 4;
            f32x4 hv = *reinterpret_cast<const f32x4*>(hxl + crow);
            nhxi4[rg] = -hv;
            f32x4 hw = *reinterpret_cast<const f32x4*>(hyl + crow);
            nhyi4[rg] = -hw;
        }

        float rpx[4][4] = {}, rpy[4][4] = {};

        // one tile's compute: ds_read fragments, MFMA, skip-test, epilogue
        auto compute_tile = [&](int k) {
            int jt = jt0 + k;
            int jb = jt * 32;
            bool band = (jt - 8 * ti) < 8;

            const char* bufc = smem + (k & (NBUF - 1)) * BUF_BYTES;
            const float* hbuf = (const float*)(bufc + H_OFF);

            float hxj[2], hyj[2];
#pragma unroll
            for (int cg = 0; cg < 2; ++cg) {
                hxj[cg] = hbuf[cg * 16 + lrow];
                hyj[cg] = hbuf[32 + cg * 16 + lrow];
            }

            bf16x8 bfx[2][2], bfy[2][2];
#pragma unroll
            for (int cg = 0; cg < 2; ++cg)
#pragma unroll
                for (int kc = 0; kc < 2; ++kc) {
                    bfx[cg][kc] = *reinterpret_cast<const bf16x8*>(bufc + offb[cg][kc]);
                    bfy[cg][kc] = *reinterpret_cast<const bf16x8*>(bufc + 4096 + offb[cg][kc]);
                }

            // C init = -(h_i + h_j); MFMA output is the full base-2 exponent
            f32x4 gx[4][2], gy[4][2];
#pragma unroll
            for (int rg = 0; rg < 4; ++rg)
#pragma unroll
                for (int cg = 0; cg < 2; ++cg) {
                    gx[rg][cg] = nhxi4[rg] - hxj[cg];
                    gy[rg][cg] = nhyi4[rg] - hyj[cg];
                }

#pragma unroll
            for (int rg = 0; rg < 4; ++rg)
#pragma unroll
                for (int cg = 0; cg < 2; ++cg)
#pragma unroll
                    for (int kc = 0; kc < 2; ++kc) {
                        gx[rg][cg] = __builtin_amdgcn_mfma_f32_16x16x32_bf16(ax[rg][kc], bfx[cg][kc], gx[rg][cg], 0, 0, 0);
                        gy[rg][cg] = __builtin_amdgcn_mfma_f32_16x16x32_bf16(ay[rg][kc], bfy[cg][kc], gy[rg][cg], 0, 0, 0);
                    }

            // max over all 64 exponents (left-nested triples -> v_max3), one branch
            float mt[16];
#pragma unroll
            for (int rg = 0; rg < 4; ++rg)
#pragma unroll
                for (int cg = 0; cg < 2; ++cg) {
                    int idx = rg * 2 + cg;
                    mt[idx]     = fmaxf(fmaxf(fmaxf(gx[rg][cg][0], gx[rg][cg][1]), gx[rg][cg][2]), gx[rg][cg][3]);
                    mt[8 + idx] = fmaxf(fmaxf(fmaxf(gy[rg][cg][0], gy[rg][cg][1]), gy[rg][cg][2]), gy[rg][cg][3]);
                }
            float m0 = fmaxf(fmaxf(fmaxf(mt[0], mt[1]), mt[2]), mt[3]);
            float m1 = fmaxf(fmaxf(fmaxf(mt[4], mt[5]), mt[6]), mt[7]);
            float m2 = fmaxf(fmaxf(fmaxf(mt[8], mt[9]), mt[10]), mt[11]);
            float m3 = fmaxf(fmaxf(fmaxf(mt[12], mt[13]), mt[14]), mt[15]);
            float mall = fmaxf(fmaxf(m0, m1), fmaxf(m2, m3));

            if (__ballot(mall >= THR)) {
                float cax[2] = {0.f, 0.f}, cay[2] = {0.f, 0.f};
#pragma unroll
                for (int rg = 0; rg < 4; ++rg)
#pragma unroll
                    for (int cg = 0; cg < 2; ++cg)
#pragma unroll
                        for (int q = 0; q < 4; ++q) {
                            float kxv = __builtin_exp2f(gx[rg][cg][q]);
                            float kyv = __builtin_exp2f(gy[rg][cg][q]);
                            rpx[rg][q] += kxv;
                            rpy[rg][q] += kyv;
                            float prod = kxv * kyv;
                            if (band) {
                                t1_1 += prod;
                            } else {
                                t1_2 += prod;
                                cax[cg] += kxv;
                                cay[cg] += kyv;
                            }
                        }
                if (!band) {
#pragma unroll
                    for (int cg = 0; cg < 2; ++cg) {
                        float vx = cax[cg], vy = cay[cg];
                        vx += __shfl_xor(vx, 16); vx += __shfl_xor(vx, 32);
                        vy += __shfl_xor(vy, 16); vy += __shfl_xor(vy, 32);
                        if (khi == 0) {
                            atomicAdd(&a_raw[l * NN + jb + cg * 16 + lrow], vx);
                            atomicAdd(&b_raw[l * NN + jb + cg * 16 + lrow], vy);
                        }
                    }
                }
            }
        };

        // prologue: stage pairs 0 and 1 (tiles 0..3, capped)
        int npro = cnt < 4 ? cnt : 4;
        for (int s = 0; s < npro; ++s)
            stage_tile(smem, s, wave, lane, Xl, Yl, hxl, hyl, (jt0 + s) * 32);

        // main loop: one barrier per PAIR of tiles
        for (int base = 0; base < cnt; base += 2) {
            if (base + 4 < cnt)
                stage_tile(smem, (base + 4) & (NBUF - 1), wave, lane, Xl, Yl, hxl, hyl, (jt0 + base + 4) * 32);
            if (base + 5 < cnt)
                stage_tile(smem, (base + 5) & (NBUF - 1), wave, lane, Xl, Yl, hxl, hyl, (jt0 + base + 5) * 32);

            // counted wait: pair `base` retired; 12/9/6/3 newest ops may remain
            int rem = cnt - base - 2;             // tiles staged beyond this pair
            if (rem >= 4)      asm volatile("s_waitcnt vmcnt(12)" ::: "memory");
            else if (rem == 3) asm volatile("s_waitcnt vmcnt(9)"  ::: "memory");
            else if (rem == 2) asm volatile("s_waitcnt vmcnt(6)"  ::: "memory");
            else if (rem == 1) asm volatile("s_waitcnt vmcnt(3)"  ::: "memory");
            else               asm volatile("s_waitcnt vmcnt(0)"  ::: "memory");
            __builtin_amdgcn_s_barrier();
            __builtin_amdgcn_sched_barrier(0);

            compute_tile(base);
            if (base + 1 < cnt) compute_tile(base + 1);
        }

        // flush row sums for this i-tile
#pragma unroll
        for (int rg = 0; rg < 4; ++rg)
#pragma unroll
            for (int q = 0; q < 4; ++q) {
                float vx = rpx[rg][q], vy = rpy[rg][q];
#pragma unroll
                for (int sh = 1; sh < 16; sh <<= 1) {
                    vx += __shfl_xor(vx, sh);
                    vy += __shfl_xor(vy, sh);
                }
                if (lrow == 0) {
                    int row = ibase + rg * 16 + khi * 4 + q;
                    atomicAdd(&a_raw[l * NN + row], vx);
                    atomicAdd(&b_raw[l * NN + row], vy);
                }
            }
    };

    // phase A: ti = p, units [u0, min(u1,c)), jt = 8p + u
    int a_lo = u0, a_hi = (u1 < c) ? u1 : c;
    if (a_lo < a_hi) run_phase(p, 8 * p + a_lo, a_hi - a_lo);

    // phase B: ti = 15-p, units [max(u0,c), u1), jt = 8(15-p) + (u - c)
    int b_lo = (u0 > c) ? u0 : c, b_hi = u1;
    if (b_lo < b_hi) run_phase(15 - p, 8 * (15 - p) + (b_lo - c), b_hi - b_lo);

    float v = t1_1 + 2.f * t1_2;
#pragma unroll
    for (int sh = 1; sh < 64; sh <<= 1) v += __shfl_xor(v, sh);
    if (lane == 0) atomicAdd(&t1[l], v);
}

// One block per l; S_l = T1 - (2/n) sum A_i B_i + (sum A)(sum B)/n^2; atomicAdd into out.
__global__ void finalize_kernel(const float* __restrict__ a_raw, const float* __restrict__ b_raw,
                                const float* __restrict__ t1, float* __restrict__ out) {
    int l = blockIdx.x;
    int t = threadIdx.x;
    int lane = t & 63, w = t >> 6;

    float sab = 0.f, sa = 0.f, sb = 0.f;
    for (int i = t; i < NN; i += 256) {
        float av = a_raw[l * NN + i], bv = b_raw[l * NN + i];
        sab = __builtin_fmaf(av, bv, sab);
        sa += av;
        sb += bv;
    }
#pragma unroll
    for (int s = 1; s < 64; s <<= 1) {
        sab += __shfl_xor(sab, s);
        sa  += __shfl_xor(sa, s);
        sb  += __shfl_xor(sb, s);
    }
    __shared__ float sh[3][4];
    if (lane == 0) { sh[0][w] = sab; sh[1][w] = sa; sh[2][w] = sb; }
    __syncthreads();
    if (t == 0) {
        float rab = sh[0][0] + sh[0][1] + sh[0][2] + sh[0][3];
        float ra  = sh[1][0] + sh[1][1] + sh[1][2] + sh[1][3];
        float rb  = sh[2][0] + sh[2][1] + sh[2][2] + sh[2][3];
        const float n = (float)NN;
        float S = t1[l] - (2.f / n) * rab + (ra * rb) / (n * n);
        atomicAdd(out, S / (4095.f * 4095.f));
    }
}

extern "C" void kernel_launch(void* const* d_in, const int* in_sizes, int n_in,
                              void* d_out, int out_size, void* d_ws, size_t ws_size,
                              hipStream_t stream) {
    const float* X = (const float*)d_in[0];
    const float* Y = (const float*)d_in[1];
    float* out = (float*)d_out;
    char* ws = (char*)d_ws;

    const size_t XB_OFF  = 0;                       // L*N*D bf16 = 8388608 B
    const size_t YB_OFF  = 8388608;
    const size_t HX_OFF  = 16777216;                // L*N fp32
    const size_t HY_OFF  = 17039360;
    const size_t A_OFF   = 17301504;                // L*N fp32
    const size_t B_OFF   = 17563648;
    const size_t T1_OFF  = 17825792;                // L fp32

    ushort* Xb  = (ushort*)(ws + XB_OFF);
    ushort* Yb  = (ushort*)(ws + YB_OFF);
    float* hx   = (float*)(ws + HX_OFF);
    float* hy   = (float*)(ws + HY_OFF);
    float* a_raw = (float*)(ws + A_OFF);
    float* b_raw = (float*)(ws + B_OFF);
    float* t1    = (float*)(ws + T1_OFF);

    // zero-init of a_raw|b_raw|t1|out is folded into prep_kernel (y==0 blocks)
    prep_kernel<<<dim3(NN, 2), 256, 0, stream>>>(X, Y, Xb, Yb, hx, hy, a_raw, out);
    hsic_tri<<<512, 256, 0, stream>>>(Xb, Yb, hx, hy, a_raw, b_raw, t1);
    finalize_kernel<<<LL, 256, 0, stream>>>(a_raw, b_raw, t1, out);
}

// Round 18
// 79.527 us; speedup vs baseline: 1.1112x; 1.0006x over previous
//
#include <hip/hip_runtime.h>
#include <hip/hip_bf16.h>

typedef __attribute__((ext_vector_type(8))) short bf16x8;
typedef __attribute__((ext_vector_type(4))) float f32x4;

#define NN 4096
#define DD 64
#define LL 16
// sqrt(log2(e)): prescaling x by this makes dot = log2(e)*<x,x'>, so
// K = exp(dot - hi - hj) becomes exp2(dots - hsi - hsj) -> bare v_exp_f32.
#define SCALE 1.2011224087864498f
// skip threshold (base-2 exponent): skipped terms <= 2^-24 each.
#define THR -24.0f

__device__ __forceinline__ ushort f2bf(float f) {
    unsigned int u = __float_as_uint(f);
    unsigned int r = u + 0x7FFFu + ((u >> 16) & 1u);
    return (ushort)(r >> 16);
}
__device__ __forceinline__ float bf2f(ushort u) {
    return __uint_as_float(((unsigned int)u) << 16);
}

__device__ __forceinline__ void gload_lds16(const void* g, void* l) {
    __builtin_amdgcn_global_load_lds((const __attribute__((address_space(1))) unsigned int*)g,
                                     (__attribute__((address_space(3))) unsigned int*)l, 16, 0, 0);
}
__device__ __forceinline__ void gload_lds4(const void* g, void* l) {
    __builtin_amdgcn_global_load_lds((const __attribute__((address_space(1))) unsigned int*)g,
                                     (__attribute__((address_space(3))) unsigned int*)l, 4, 0, 0);
}

// Transpose (N,D,L) fp32 -> (L,N,D) bf16 with per-row 16B-chunk XOR swizzle
// (chunk co of row n stored at co ^ (n&7)), values prescaled by SCALE, and
// h[l][n] = 0.5 * sum_d xs_bf16^2 (fp32, from the SAME bf16 values MFMA sees).
// Also zero-inits the accumulator region (a_raw|b_raw|t1 contiguous) and out,
// replacing two hipMemsetAsync launches (prep completes before hsic_tri).
__global__ void prep_kernel(const float* __restrict__ X, const float* __restrict__ Y,
                            ushort* __restrict__ Xb, ushort* __restrict__ Yb,
                            float* __restrict__ hx, float* __restrict__ hy,
                            float* __restrict__ zacc, float* __restrict__ out) {
    const float* in = blockIdx.y ? Y : X;
    ushort* outb    = blockIdx.y ? Yb : Xb;
    float* h        = blockIdx.y ? hy : hx;

    __shared__ float lds[64 * 17];
    __shared__ float psum[16][17];

    int n = blockIdx.x;
    int t = threadIdx.x;
    const float* row = in + (size_t)n * (DD * LL);

    // fold the memsets: zacc = a_raw|b_raw|t1 = 131088 floats, contiguous
    if (blockIdx.y == 0) {
        if (t < 32) zacc[n * 32 + t] = 0.f;                    // 4096*32 = 131072
        if (n == 0) {
            if (t >= 32 && t < 48) zacc[131072 + (t - 32)] = 0.f;  // t1[16]
            if (t == 48) out[0] = 0.f;
        }
    }

    // vectorized load: 256 threads x float4 = 1024 floats (e = d*16 + l)
    {
        float4 v = *reinterpret_cast<const float4*>(row + 4 * t);
        int d = t >> 2, l0 = (t & 3) * 4;
        lds[d * 17 + l0 + 0] = v.x;
        lds[d * 17 + l0 + 1] = v.y;
        lds[d * 17 + l0 + 2] = v.z;
        lds[d * 17 + l0 + 3] = v.w;
    }
    __syncthreads();

    int l = t >> 4, c = t & 15;
    float p = 0.f;
    ushort4 w;
    {
        float v0 = lds[(c * 4 + 0) * 17 + l] * SCALE;
        float v1 = lds[(c * 4 + 1) * 17 + l] * SCALE;
        float v2 = lds[(c * 4 + 2) * 17 + l] * SCALE;
        float v3 = lds[(c * 4 + 3) * 17 + l] * SCALE;
        ushort u0 = f2bf(v0), u1 = f2bf(v1), u2 = f2bf(v2), u3 = f2bf(v3);
        float b0 = bf2f(u0), b1 = bf2f(u1), b2 = bf2f(u2), b3 = bf2f(u3);
        p = b0 * b0 + b1 * b1 + b2 * b2 + b3 * b3;
        w.x = u0; w.y = u1; w.z = u2; w.w = u3;
    }
    int cs = (c >> 1) ^ (n & 7);
    *reinterpret_cast<ushort4*>(outb + ((size_t)l * NN + n) * DD + cs * 8 + (c & 1) * 4) = w;

    psum[l][c] = p;
    __syncthreads();
    if (t < 16) {
        float s = 0.f;
#pragma unroll
        for (int i = 0; i < 16; ++i) s += psum[t][i];
        h[t * NN + n] = 0.5f * s;
    }
}

// LDS: 8 buffers x 8448 B; TWO tiles consumed per barrier, pair m+2 staged
// at the top of pair-iteration m (buffers (2m+4)&7,(2m+5)&7 never collide with
// pair m reads or the slowest wave's pair m-1 reads).
// Per buffer: [X 32x128B swizzled][Y 32x128B][h 256B = hx32,hy32].
#define BUF_BYTES 8448
#define H_OFF 8192
#define NBUF 8

// Uniform 3 VMEM ops per wave per stage (2x gload16 + 1x gload4 h-dup).
__device__ __forceinline__ void stage_tile(char* smem, int buf, int wave, int lane,
                                           const ushort* __restrict__ Xl, const ushort* __restrict__ Yl,
                                           const float* __restrict__ hxl, const float* __restrict__ hyl,
                                           int jb) {
    char* base = smem + buf * BUF_BYTES;
    const ushort* mat = (wave < 2) ? Xl : Yl;
#pragma unroll
    for (int q = 0; q < 2; ++q) {
        int ridx = wave * 2 + q;                  // 0..7 -> mat*4 + rowgroup
        int rbase = (ridx & 3) * 8;
        const ushort* src = mat + (size_t)(jb + rbase + (lane >> 3)) * DD + (lane & 7) * 8;
        gload_lds16(src, base + ridx * 1024);
    }
    // all waves duplicate-stage h (identical data, benign race, uniform vmcnt count)
    const float* hsrc = (lane < 32) ? (hxl + jb + lane) : (hyl + jb + (lane - 32));
    gload_lds4(hsrc, base + H_OFF);
}

// Triangular fused kernel, 256-row i-tiles. Grid = 16 l x 8 pairs x 4 segs = 512
// (R5 mapping). Pair p owns i-tiles {p, 15-p}; per i-tile ti, j-units jt in
// [8ti, 128); pair total 136 = 4 segments x 34 contiguous. Band units
// (jt-8ti < 8): diagonal 256x256 block computed fully, weight 1, row sums only.
// Strict-upper: weight 2 for T1, col sums mirrored. Per wave: 64i x 32j per
// tile, 2 tiles per barrier. [Best measured config: tri 65.0 us, round 10/15.]
__global__ __launch_bounds__(256, 2) void hsic_tri(
    const ushort* __restrict__ Xb, const ushort* __restrict__ Yb,
    const float* __restrict__ hx, const float* __restrict__ hy,
    float* __restrict__ a_raw, float* __restrict__ b_raw, float* __restrict__ t1) {

    int blk = blockIdx.x;                       // 512
    int l = (blk & 7) * 2 + ((blk >> 3) & 1);   // XCD-pinned l pair
    int rest = blk >> 4;                        // 0..31
    int p = rest >> 2;                          // 0..7
    int seg = rest & 3;                         // 0..3
    int c = 128 - 8 * p;                        // units in phase A (ti = p)
    int u0 = seg * 34, u1 = u0 + 34;

    int wave = threadIdx.x >> 6;
    int lane = threadIdx.x & 63;
    int lrow = lane & 15;
    int khi  = lane >> 4;

    const ushort* Xl = Xb + (size_t)l * (NN * DD);
    const ushort* Yl = Yb + (size_t)l * (NN * DD);
    const float* hxl = hx + l * NN;
    const float* hyl = hy + l * NN;

    __shared__ __align__(16) char smem[NBUF * BUF_BYTES];

    float t1_1 = 0.f, t1_2 = 0.f;

    // per-lane LDS byte offsets for B fragments (constant)
    int offb[2][2];
#pragma unroll
    for (int cg = 0; cg < 2; ++cg)
#pragma unroll
        for (int kc = 0; kc < 2; ++kc)
            offb[cg][kc] = (cg * 16 + lrow) * 128 + (((kc * 4 + khi) ^ (lrow & 7)) * 16);

    auto run_phase = [&](int ti, int jt0, int cnt) {
        __syncthreads();                  // protect buffers from previous phase
        int ibase = ti * 256 + wave * 64;

        bf16x8 ax[4][2], ay[4][2];
        f32x4 nhxi4[4], nhyi4[4];
#pragma unroll
        for (int rg = 0; rg < 4; ++rg) {
            int arow = ibase + rg * 16 + lrow;
#pragma unroll
            for (int kc = 0; kc < 2; ++kc) {
                int cs = (kc * 4 + khi) ^ (arow & 7);
                ax[rg][kc] = *reinterpret_cast<const bf16x8*>(Xl + (size_t)arow * DD + cs * 8);
                ay[rg][kc] = *reinterpret_cast<const bf16x8*>(Yl + (size_t)arow * DD + cs * 8);
            }
            int crow = ibase + rg * 16 + khi * 4;
            f32x4 hv = *reinterpret_cast<const f32x4*>(hxl + crow);
            nhxi4[rg] = -hv;
            f32x4 hw = *reinterpret_cast<const f32x4*>(hyl + crow);
            nhyi4[rg] = -hw;
        }

        float rpx[4][4] = {}, rpy[4][4] = {};

        // one tile's compute: ds_read fragments, MFMA, skip-test, epilogue
        auto compute_tile = [&](int k) {
            int jt = jt0 + k;
            int jb = jt * 32;
            bool band = (jt - 8 * ti) < 8;

            const char* bufc = smem + (k & (NBUF - 1)) * BUF_BYTES;
            const float* hbuf = (const float*)(bufc + H_OFF);

            float hxj[2], hyj[2];
#pragma unroll
            for (int cg = 0; cg < 2; ++cg) {
                hxj[cg] = hbuf[cg * 16 + lrow];
                hyj[cg] = hbuf[32 + cg * 16 + lrow];
            }

            bf16x8 bfx[2][2], bfy[2][2];
#pragma unroll
            for (int cg = 0; cg < 2; ++cg)
#pragma unroll
                for (int kc = 0; kc < 2; ++kc) {
                    bfx[cg][kc] = *reinterpret_cast<const bf16x8*>(bufc + offb[cg][kc]);
                    bfy[cg][kc] = *reinterpret_cast<const bf16x8*>(bufc + 4096 + offb[cg][kc]);
                }

            // C init = -(h_i + h_j); MFMA output is the full base-2 exponent
            f32x4 gx[4][2], gy[4][2];
#pragma unroll
            for (int rg = 0; rg < 4; ++rg)
#pragma unroll
                for (int cg = 0; cg < 2; ++cg) {
                    gx[rg][cg] = nhxi4[rg] - hxj[cg];
                    gy[rg][cg] = nhyi4[rg] - hyj[cg];
                }

#pragma unroll
            for (int rg = 0; rg < 4; ++rg)
#pragma unroll
                for (int cg = 0; cg < 2; ++cg)
#pragma unroll
                    for (int kc = 0; kc < 2; ++kc) {
                        gx[rg][cg] = __builtin_amdgcn_mfma_f32_16x16x32_bf16(ax[rg][kc], bfx[cg][kc], gx[rg][cg], 0, 0, 0);
                        gy[rg][cg] = __builtin_amdgcn_mfma_f32_16x16x32_bf16(ay[rg][kc], bfy[cg][kc], gy[rg][cg], 0, 0, 0);
                    }

            // max over all 64 exponents (left-nested triples -> v_max3), one branch
            float mt[16];
#pragma unroll
            for (int rg = 0; rg < 4; ++rg)
#pragma unroll
                for (int cg = 0; cg < 2; ++cg) {
                    int idx = rg * 2 + cg;
                    mt[idx]     = fmaxf(fmaxf(fmaxf(gx[rg][cg][0], gx[rg][cg][1]), gx[rg][cg][2]), gx[rg][cg][3]);
                    mt[8 + idx] = fmaxf(fmaxf(fmaxf(gy[rg][cg][0], gy[rg][cg][1]), gy[rg][cg][2]), gy[rg][cg][3]);
                }
            float m0 = fmaxf(fmaxf(fmaxf(mt[0], mt[1]), mt[2]), mt[3]);
            float m1 = fmaxf(fmaxf(fmaxf(mt[4], mt[5]), mt[6]), mt[7]);
            float m2 = fmaxf(fmaxf(fmaxf(mt[8], mt[9]), mt[10]), mt[11]);
            float m3 = fmaxf(fmaxf(fmaxf(mt[12], mt[13]), mt[14]), mt[15]);
            float mall = fmaxf(fmaxf(m0, m1), fmaxf(m2, m3));

            if (__ballot(mall >= THR)) {
                float cax[2] = {0.f, 0.f}, cay[2] = {0.f, 0.f};
#pragma unroll
                for (int rg = 0; rg < 4; ++rg)
#pragma unroll
                    for (int cg = 0; cg < 2; ++cg)
#pragma unroll
                        for (int q = 0; q < 4; ++q) {
                            float kxv = __builtin_exp2f(gx[rg][cg][q]);
                            float kyv = __builtin_exp2f(gy[rg][cg][q]);
                            rpx[rg][q] += kxv;
                            rpy[rg][q] += kyv;
                            float prod = kxv * kyv;
                            if (band) {
                                t1_1 += prod;
                            } else {
                                t1_2 += prod;
                                cax[cg] += kxv;
                                cay[cg] += kyv;
                            }
                        }
                if (!band) {
#pragma unroll
                    for (int cg = 0; cg < 2; ++cg) {
                        float vx = cax[cg], vy = cay[cg];
                        vx += __shfl_xor(vx, 16); vx += __shfl_xor(vx, 32);
                        vy += __shfl_xor(vy, 16); vy += __shfl_xor(vy, 32);
                        if (khi == 0) {
                            atomicAdd(&a_raw[l * NN + jb + cg * 16 + lrow], vx);
                            atomicAdd(&b_raw[l * NN + jb + cg * 16 + lrow], vy);
                        }
                    }
                }
            }
        };

        // prologue: stage pairs 0 and 1 (tiles 0..3, capped)
        int npro = cnt < 4 ? cnt : 4;
        for (int s = 0; s < npro; ++s)
            stage_tile(smem, s, wave, lane, Xl, Yl, hxl, hyl, (jt0 + s) * 32);

        // main loop: one barrier per PAIR of tiles
        for (int base = 0; base < cnt; base += 2) {
            if (base + 4 < cnt)
                stage_tile(smem, (base + 4) & (NBUF - 1), wave, lane, Xl, Yl, hxl, hyl, (jt0 + base + 4) * 32);
            if (base + 5 < cnt)
                stage_tile(smem, (base + 5) & (NBUF - 1), wave, lane, Xl, Yl, hxl, hyl, (jt0 + base + 5) * 32);

            // counted wait: pair `base` retired; 12/9/6/3 newest ops may remain
            int rem = cnt - base - 2;             // tiles staged beyond this pair
            if (rem >= 4)      asm volatile("s_waitcnt vmcnt(12)" ::: "memory");
            else if (rem == 3) asm volatile("s_waitcnt vmcnt(9)"  ::: "memory");
            else if (rem == 2) asm volatile("s_waitcnt vmcnt(6)"  ::: "memory");
            else if (rem == 1) asm volatile("s_waitcnt vmcnt(3)"  ::: "memory");
            else               asm volatile("s_waitcnt vmcnt(0)"  ::: "memory");
            __builtin_amdgcn_s_barrier();
            __builtin_amdgcn_sched_barrier(0);

            compute_tile(base);
            if (base + 1 < cnt) compute_tile(base + 1);
        }

        // flush row sums for this i-tile
#pragma unroll
        for (int rg = 0; rg < 4; ++rg)
#pragma unroll
            for (int q = 0; q < 4; ++q) {
                float vx = rpx[rg][q], vy = rpy[rg][q];
#pragma unroll
                for (int sh = 1; sh < 16; sh <<= 1) {
                    vx += __shfl_xor(vx, sh);
                    vy += __shfl_xor(vy, sh);
                }
                if (lrow == 0) {
                    int row = ibase + rg * 16 + khi * 4 + q;
                    atomicAdd(&a_raw[l * NN + row], vx);
                    atomicAdd(&b_raw[l * NN + row], vy);
                }
            }
    };

    // phase A: ti = p, units [u0, min(u1,c)), jt = 8p + u
    int a_lo = u0, a_hi = (u1 < c) ? u1 : c;
    if (a_lo < a_hi) run_phase(p, 8 * p + a_lo, a_hi - a_lo);

    // phase B: ti = 15-p, units [max(u0,c), u1), jt = 8(15-p) + (u - c)
    int b_lo = (u0 > c) ? u0 : c, b_hi = u1;
    if (b_lo < b_hi) run_phase(15 - p, 8 * (15 - p) + (b_lo - c), b_hi - b_lo);

    float v = t1_1 + 2.f * t1_2;
#pragma unroll
    for (int sh = 1; sh < 64; sh <<= 1) v += __shfl_xor(v, sh);
    if (lane == 0) atomicAdd(&t1[l], v);
}

// One block per l; S_l = T1 - (2/n) sum A_i B_i + (sum A)(sum B)/n^2; atomicAdd into out.
__global__ void finalize_kernel(const float* __restrict__ a_raw, const float* __restrict__ b_raw,
                                const float* __restrict__ t1, float* __restrict__ out) {
    int l = blockIdx.x;
    int t = threadIdx.x;
    int lane = t & 63, w = t >> 6;

    float sab = 0.f, sa = 0.f, sb = 0.f;
    for (int i = t; i < NN; i += 256) {
        float av = a_raw[l * NN + i], bv = b_raw[l * NN + i];
        sab = __builtin_fmaf(av, bv, sab);
        sa += av;
        sb += bv;
    }
#pragma unroll
    for (int s = 1; s < 64; s <<= 1) {
        sab += __shfl_xor(sab, s);
        sa  += __shfl_xor(sa, s);
        sb  += __shfl_xor(sb, s);
    }
    __shared__ float sh[3][4];
    if (lane == 0) { sh[0][w] = sab; sh[1][w] = sa; sh[2][w] = sb; }
    __syncthreads();
    if (t == 0) {
        float rab = sh[0][0] + sh[0][1] + sh[0][2] + sh[0][3];
        float ra  = sh[1][0] + sh[1][1] + sh[1][2] + sh[1][3];
        float rb  = sh[2][0] + sh[2][1] + sh[2][2] + sh[2][3];
        const float n = (float)NN;
        float S = t1[l] - (2.f / n) * rab + (ra * rb) / (n * n);
        atomicAdd(out, S / (4095.f * 4095.f));
    }
}

extern "C" void kernel_launch(void* const* d_in, const int* in_sizes, int n_in,
                              void* d_out, int out_size, void* d_ws, size_t ws_size,
                              hipStream_t stream) {
    const float* X = (const float*)d_in[0];
    const float* Y = (const float*)d_in[1];
    float* out = (float*)d_out;
    char* ws = (char*)d_ws;

    const size_t XB_OFF  = 0;                       // L*N*D bf16 = 8388608 B
    const size_t YB_OFF  = 8388608;
    const size_t HX_OFF  = 16777216;                // L*N fp32
    const size_t HY_OFF  = 17039360;
    const size_t A_OFF   = 17301504;                // L*N fp32
    const size_t B_OFF   = 17563648;
    const size_t T1_OFF  = 17825792;                // L fp32

    ushort* Xb  = (ushort*)(ws + XB_OFF);
    ushort* Yb  = (ushort*)(ws + YB_OFF);
    float* hx   = (float*)(ws + HX_OFF);
    float* hy   = (float*)(ws + HY_OFF);
    float* a_raw = (float*)(ws + A_OFF);
    float* b_raw = (float*)(ws + B_OFF);
    float* t1    = (float*)(ws + T1_OFF);

    // zero-init of a_raw|b_raw|t1|out is folded into prep_kernel (y==0 blocks)
    prep_kernel<<<dim3(NN, 2), 256, 0, stream>>>(X, Y, Xb, Yb, hx, hy, a_raw, out);
    hsic_tri<<<512, 256, 0, stream>>>(Xb, Yb, hx, hy, a_raw, b_raw, t1);
    finalize_kernel<<<LL, 256, 0, stream>>>(a_raw, b_raw, t1, out);
}